// Round 19
// baseline (4567.086 us; speedup 1.0000x reference)
//
#include <hip/hip_runtime.h>

// AdaptiveDownsampling: farthest point sampling (B=8, N=8192, m=4096) + gather.
// Outputs concatenated flat: dp [8,4096,3] then df [8,4096,256], float32.
//
// r2: np reference computes in float64 -> exact path must be fp64.
// r6: fp32 screen + rare exact fp64 path. 5275 us.
// r7: DPP wave max, packed-fp32 screen, precomputed margin. 4239 us.
// r8: FAILED (5264): 1-barrier + 3 full ladders/wave. VALU tax.
// r9: dirty-wave caching + fused ladders. 4198 us.
// r10: FAILED (5165): cull test on the pacing path.
// r11: FAILED (6141): payload atomics w/ VGPR-cached coords -> spill.
// r12/r13: FAILED (5532/5518): bundled changes; waves_per_eu inert.
// r14: r9 + ballot/readlane for ladders 2+3. 3925 us.
// r15: FAILED (4689): coord extraction + u64 atomics INSIDE the A->B
//     barrier window. Lesson: barrier-window work costs full price.
// r16: 1 barrier, 0 atomics, per-wave slots + block ladder. 3983 us (~flat
//     vs r14) -> sync COUNT is not the lever; ~2300cy/iter floor across 3
//     structures. Post-barrier tail still ends in dependent s_pts RT.
// r17: coords ride IN the slot (widened to 2x uint4). Extraction in the
//     DIRTY-REDUCE (overlapped, not barrier window): wj switch + 3
//     readlanes -> SGPRs sx/sy/sz (wave-uniform, zero VGPR pressure).
//     Publish = plain ds_write by lanes 0/1. Post-barrier: read both slot
//     halves in parallel, ladder, 5 readlanes -> winner idx+coords. s_pts
//     (96KB + staging + dependent RT) deleted. Bits identical: coords pass
//     reg->readlane->LDS->readlane unchanged.
//     (Fourth submit: three GPU acquisition timeouts.)

typedef float v2f __attribute__((ext_vector_type(2)));

#define BATCH 8
#define NPTS  8192
#define MSEL  4096
#define NFEAT 256
#define BLOCK 1024
#define NWAVE (BLOCK / 64)

// fp64 square, opaque to the compiler so no v_fma_f64 contraction can merge
// the following adds (numpy float64 does separate mul / add / add).
__device__ __forceinline__ double sqd(double x) {
    double r;
    asm("v_mul_f64 %0, %1, %1" : "=v"(r) : "v"(x));
    return r;
}

// Exact 64-lane u32 max via fused DPP max ops, result wave-uniform in SGPR.
// bound_ctrl:0 => out-of-range DPP sources read 0 (identity for unsigned max).
// Requires full exec / uniform control flow at the call site.
__device__ __forceinline__ unsigned wave_umax_rl(unsigned v) {
    unsigned s;
    asm volatile(
        "s_nop 1\n\t"
        "v_max_u32_dpp %1, %1, %1 row_shr:1  row_mask:0xf bank_mask:0xf bound_ctrl:0\n\t"
        "s_nop 1\n\t"
        "v_max_u32_dpp %1, %1, %1 row_shr:2  row_mask:0xf bank_mask:0xf bound_ctrl:0\n\t"
        "s_nop 1\n\t"
        "v_max_u32_dpp %1, %1, %1 row_shr:4  row_mask:0xf bank_mask:0xf bound_ctrl:0\n\t"
        "s_nop 1\n\t"
        "v_max_u32_dpp %1, %1, %1 row_shr:8  row_mask:0xf bank_mask:0xf bound_ctrl:0\n\t"
        "s_nop 1\n\t"
        "v_max_u32_dpp %1, %1, %1 row_bcast:15 row_mask:0xf bank_mask:0xf bound_ctrl:0\n\t"
        "s_nop 1\n\t"
        "v_max_u32_dpp %1, %1, %1 row_bcast:31 row_mask:0xf bank_mask:0xf bound_ctrl:0\n\t"
        "s_nop 1\n\t"
        "v_readlane_b32 %0, %1, 63"
        : "=s"(s), "+v"(v));
    return s;
}

__launch_bounds__(BLOCK, 1)
__global__ void fps_kernel(const float* __restrict__ pts,   // [B, N, 3]
                           float* __restrict__ dp,          // [B, M, 3]
                           int* __restrict__ idx_out)       // [B, M]
{
    __shared__ uint4 s_slotA[2][NWAVE];    // (whi, wlo, wn, xbits)
    __shared__ uint4 s_slotB[2][NWAVE];    // (ybits, zbits, 0, 0)

    const int b    = blockIdx.x;
    const int tid  = threadIdx.x;
    const int lane = tid & 63;
    const int wid  = tid >> 6;
    const float* p = pts + (size_t)b * NPTS * 3;

    // Coords as float2 pairs (slots 2P, 2P+1) -> packed-fp32 screen.
    // mind (fp64 exact) + mfm (pre-margined fp32 screen threshold) per slot.
#define DECLP(P, J0, J1) \
    v2f pxp##P = { p[(tid + J0 * 1024) * 3 + 0], p[(tid + J1 * 1024) * 3 + 0] }; \
    v2f pyp##P = { p[(tid + J0 * 1024) * 3 + 1], p[(tid + J1 * 1024) * 3 + 1] }; \
    v2f pzp##P = { p[(tid + J0 * 1024) * 3 + 2], p[(tid + J1 * 1024) * 3 + 2] };
    DECLP(0, 0, 1) DECLP(1, 2, 3) DECLP(2, 4, 5) DECLP(3, 6, 7)
#undef DECLP
    double mind0 = 1e10, mind1 = 1e10, mind2 = 1e10, mind3 = 1e10;
    double mind4 = 1e10, mind5 = 1e10, mind6 = 1e10, mind7 = 1e10;
    float  mfm0 = 1.0001e10f, mfm1 = 1.0001e10f, mfm2 = 1.0001e10f, mfm3 = 1.0001e10f;
    float  mfm4 = 1.0001e10f, mfm5 = 1.0001e10f, mfm6 = 1.0001e10f, mfm7 = 1.0001e10f;

    // Selection 0 is point 0 (deterministic start).
    float cx = p[0], cy = p[1], cz = p[2];
    if (tid == 0) {
        dp[(size_t)b * MSEL * 3 + 0] = cx;
        dp[(size_t)b * MSEL * 3 + 1] = cy;
        dp[(size_t)b * MSEL * 3 + 2] = cz;
        idx_out[b * MSEL + 0] = 0;
    }

    const int wavebase = __builtin_amdgcn_readfirstlane((int)tid);  // lane0's tid

    double   tbv   = 0.0;          // cached thread-local max of mind0..7
    bool     dirty = true;         // lane updated since last wave reduce
    unsigned whi = 0u, wlo = 0u;   // cached wave max (double bits), SGPR
    unsigned wn  = 0x7fffffffu;    // cached wave min-index-at-max, SGPR
    unsigned sx = 0u, sy = 0u, sz = 0u;   // cached winner coord bits, SGPR

    __syncthreads();   // (slot arrays written every iter before first read)

    for (int k = 1; k < MSEL; ++k) {
        const v2f cx2 = {cx, cx}, cy2 = {cy, cy}, cz2 = {cz, cz};

        // --- packed fp32 screen; exact fp64 update only on trigger (r9) ---
#define EX64(PX, PY, PZ, J) { \
        const double ddx = (double)(PX) - (double)cx; \
        const double ddy = (double)(PY) - (double)cy; \
        const double ddz = (double)(PZ) - (double)cz; \
        const double dd  = (sqd(ddx) + sqd(ddy)) + sqd(ddz); \
        if (dd < mind##J) { mind##J = dd; mfm##J = (float)dd * 1.0001f; dirty = true; } }
#define UPDP(P, J0, J1) { \
        const v2f dx = pxp##P - cx2, dy = pyp##P - cy2, dz = pzp##P - cz2; \
        const v2f d  = dx * dx + dy * dy + dz * dz; \
        if (d.x < mfm##J0) EX64(pxp##P.x, pyp##P.x, pzp##P.x, J0) \
        if (d.y < mfm##J1) EX64(pxp##P.y, pyp##P.y, pzp##P.y, J1) }
        UPDP(0, 0, 1) UPDP(1, 2, 3) UPDP(2, 4, 5) UPDP(3, 6, 7)
#undef UPDP
#undef EX64

        // --- wave reduce only if some lane in this wave updated (r14) ---
        if (__any(dirty)) {
            const double a0 = fmax(mind0, mind1), a1 = fmax(mind2, mind3);
            const double a2 = fmax(mind4, mind5), a3 = fmax(mind6, mind7);
            tbv = fmax(fmax(a0, a1), fmax(a2, a3));
            dirty = false;

            const unsigned long long tb = (unsigned long long)__double_as_longlong(tbv);
            const unsigned thi = (unsigned)(tb >> 32);
            const unsigned tlo = (unsigned)tb;
            whi = wave_umax_rl(thi);

            // per-lane min global idx among THIS lane's slots at its own max
            // (branch-free cndmask chain; numpy tie-break: scan high slot ->
            // low so the smallest index wins last assignment).
            unsigned n = 0x7fffffffu;
            if (mind7 == tbv) n = tid + 7 * 1024;
            if (mind6 == tbv) n = tid + 6 * 1024;
            if (mind5 == tbv) n = tid + 5 * 1024;
            if (mind4 == tbv) n = tid + 4 * 1024;
            if (mind3 == tbv) n = tid + 3 * 1024;
            if (mind2 == tbv) n = tid + 2 * 1024;
            if (mind1 == tbv) n = tid + 1 * 1024;
            if (mind0 == tbv) n = tid;

            int wL;
            const unsigned long long hiown = __ballot(thi == whi);
            if (__popcll(hiown) == 1) {   // unique hi-owner lane (typical)
                wL  = (int)(__ffsll(hiown) - 1);
                wlo = (unsigned)__builtin_amdgcn_readlane((int)tlo, wL);
                wn  = (unsigned)__builtin_amdgcn_readlane((int)n,   wL);
            } else {            // exact fallback on multi-lane hi ties
                wlo = wave_umax_rl(thi == whi ? tlo : 0u);
                const unsigned ng = (thi == whi && tlo == wlo) ? n : 0x7fffffffu;
                wn = ~wave_umax_rl(~ng);   // min over owner lanes
                wL = (int)(__ffsll(__ballot(thi == whi && tlo == wlo && n == wn)) - 1);
            }

            // extract winner coords (uniform wj switch, 3 readlanes -> SGPR).
            // Runs OVERLAPPED (pre-publish), not in a barrier window (r15!).
            const int wj = (int)((wn - (unsigned)(wavebase + wL)) >> 10);
#define RL(V) ((unsigned)__builtin_amdgcn_readlane((int)__float_as_uint(V), wL))
            switch (wj) {
              case 0: sx = RL(pxp0.x); sy = RL(pyp0.x); sz = RL(pzp0.x); break;
              case 1: sx = RL(pxp0.y); sy = RL(pyp0.y); sz = RL(pzp0.y); break;
              case 2: sx = RL(pxp1.x); sy = RL(pyp1.x); sz = RL(pzp1.x); break;
              case 3: sx = RL(pxp1.y); sy = RL(pyp1.y); sz = RL(pzp1.y); break;
              case 4: sx = RL(pxp2.x); sy = RL(pyp2.x); sz = RL(pzp2.x); break;
              case 5: sx = RL(pxp2.y); sy = RL(pyp2.y); sz = RL(pzp2.y); break;
              case 6: sx = RL(pxp3.x); sy = RL(pyp3.x); sz = RL(pzp3.x); break;
              default: sx = RL(pxp3.y); sy = RL(pyp3.y); sz = RL(pzp3.y); break;
            }
#undef RL
        }

        // --- publish cached wave result to own slot; ONE barrier ---
        const int buf = k & 1;
        if (lane == 0)      s_slotA[buf][wid] = make_uint4(whi, wlo, wn, sx);
        else if (lane == 1) s_slotB[buf][wid] = make_uint4(sy, sz, 0u, 0u);
        __syncthreads();

        // --- block reduce over 16 entries in every wave (entries duplicated
        //     4x across lane groups; lower 16 bits of ballots cover each
        //     entry exactly once) ---
        const int e = lane & (NWAVE - 1);
        const uint4 entA = s_slotA[buf][e];
        const uint4 entB = s_slotB[buf][e];
        const unsigned bhi = wave_umax_rl(entA.x);
        unsigned blo, bn, bx, by, bz;
        const unsigned own16 = (unsigned)__ballot(entA.x == bhi) & 0xFFFFu;
        if (__popc(own16) == 1) {   // unique hi-winner entry (typical)
            const int L = __ffs(own16) - 1;
            blo = (unsigned)__builtin_amdgcn_readlane((int)entA.y, L);
            bn  = (unsigned)__builtin_amdgcn_readlane((int)entA.z, L);
            bx  = (unsigned)__builtin_amdgcn_readlane((int)entA.w, L);
            by  = (unsigned)__builtin_amdgcn_readlane((int)entB.x, L);
            bz  = (unsigned)__builtin_amdgcn_readlane((int)entB.y, L);
        } else {                    // exact fallback on hi ties across waves
            blo = wave_umax_rl(entA.x == bhi ? entA.y : 0u);
            const unsigned ng = (entA.x == bhi && entA.y == blo) ? entA.z : 0xffffffffu;
            bn = ~wave_umax_rl(~ng);   // min idx among full-match entries
            const unsigned m16 = (unsigned)__ballot(
                entA.x == bhi && entA.y == blo && entA.z == bn) & 0xFFFFu;
            const int L2 = __ffs(m16) - 1;
            bx = (unsigned)__builtin_amdgcn_readlane((int)entA.w, L2);
            by = (unsigned)__builtin_amdgcn_readlane((int)entB.x, L2);
            bz = (unsigned)__builtin_amdgcn_readlane((int)entB.y, L2);
        }

        cx = __uint_as_float(bx);
        cy = __uint_as_float(by);
        cz = __uint_as_float(bz);
        if (tid == 0) {
            idx_out[b * MSEL + k] = (int)bn;
            float* o = dp + ((size_t)b * MSEL + k) * 3;
            o[0] = cx; o[1] = cy; o[2] = cz;
        }
    }
}

// One wave per selected row; lane i moves one float4 (64 * 16B = 1024B = full row).
__global__ void gather_kernel(const float* __restrict__ feats,  // [B, N, C]
                              const int* __restrict__ idx,      // [B, M]
                              float* __restrict__ df)           // [B, M, C]
{
    const int row  = blockIdx.x * 4 + (threadIdx.x >> 6);  // [0, B*M)
    const int lane = threadIdx.x & 63;
    const int b    = row >> 12;         // MSEL = 4096 rows per batch
    const int src  = idx[row];
    const float4* s = (const float4*)(feats + ((size_t)b * NPTS + src) * NFEAT);
    float4*       d = (float4*)(df + (size_t)row * NFEAT);
    d[lane] = s[lane];
}

extern "C" void kernel_launch(void* const* d_in, const int* in_sizes, int n_in,
                              void* d_out, int out_size, void* d_ws, size_t ws_size,
                              hipStream_t stream)
{
    const float* points   = (const float*)d_in[0];   // [8, 8192, 3]
    const float* features = (const float*)d_in[1];   // [8, 8192, 256]
    float* out = (float*)d_out;
    float* dp  = out;                                // [8, 4096, 3]
    float* df  = out + (size_t)BATCH * MSEL * 3;     // [8, 4096, 256]
    int*   idx_ws = (int*)d_ws;                      // [8, 4096] = 128 KB scratch

    fps_kernel<<<BATCH, BLOCK, 0, stream>>>(points, dp, idx_ws);
    gather_kernel<<<(BATCH * MSEL) / 4, 256, 0, stream>>>(features, idx_ws, df);
}